// Round 1
// baseline (73.483 us; speedup 1.0000x reference)
//
#include <hip/hip_runtime.h>
#include <hip/hip_bf16.h>

// Problem constants (from reference): B=64, T=8192, L=DEC_LEN=64, NWIN=T-L=8128
constexpr int B_SZ  = 64;
constexpr int T_SZ  = 8192;
constexpr int L_SZ  = 64;
constexpr int NWIN  = T_SZ - L_SZ;   // 8128, divisible by 4

// One block per batch. 256 threads. Stage x row in LDS, y in registers.
// Each thread handles groups of 4 consecutive windows: s0 = 4*tid + 1024*k.
// Packed argmin key: (float_bits(dist) << 32) | s  — dist >= 0 so bit pattern
// preserves float order; ties break to smallest s (matches np.argmin).
__global__ __launch_bounds__(256)
void window_match_kernel(const float* __restrict__ X_in,
                         const float* __restrict__ X_out,
                         float* __restrict__ out)
{
    __shared__ float xs[T_SZ];                 // 32 KB
    __shared__ float ys[L_SZ];
    __shared__ unsigned long long wred[4];
    __shared__ int win_start;

    const int b   = blockIdx.x;
    const int tid = threadIdx.x;

    // Stage x[b, :] into LDS with float4 loads (coalesced, 16B/lane)
    const float4* xg  = reinterpret_cast<const float4*>(X_in + (size_t)b * T_SZ);
    float4*       xs4 = reinterpret_cast<float4*>(xs);
    #pragma unroll
    for (int i = 0; i < T_SZ / 4 / 256; ++i)
        xs4[tid + i * 256] = xg[tid + i * 256];

    if (tid < L_SZ) ys[tid] = X_out[(size_t)b * L_SZ + tid];
    __syncthreads();

    // y into registers (LDS broadcast reads: all lanes same address -> free)
    float y[L_SZ];
    #pragma unroll
    for (int j = 0; j < L_SZ; ++j) y[j] = ys[j];

    unsigned long long best = ~0ull;

    // 8 rounds: 256 threads * 4 windows = 1024 windows per round; 8128 total.
    for (int k = 0; k < 8; ++k) {
        const int s0 = 4 * tid + 1024 * k;     // multiple of 4 -> float4-aligned
        if (s0 < NWIN) {                       // s0 <= 8124 -> reads up to xs[8191]
            // Load x[s0 .. s0+67] as 17 float4 (reused across 4 windows)
            float xv[68];
            const float4* p = reinterpret_cast<const float4*>(xs + s0);
            #pragma unroll
            for (int i = 0; i < 17; ++i) {
                float4 v = p[i];
                xv[4 * i + 0] = v.x;
                xv[4 * i + 1] = v.y;
                xv[4 * i + 2] = v.z;
                xv[4 * i + 3] = v.w;
            }
            #pragma unroll
            for (int w = 0; w < 4; ++w) {
                float d = 0.0f;
                #pragma unroll
                for (int j = 0; j < L_SZ; ++j) {
                    const float t = xv[w + j] - y[j];
                    d = fmaf(t, t, d);
                }
                const unsigned long long key =
                    ((unsigned long long)__float_as_uint(d) << 32) |
                    (unsigned int)(s0 + w);
                best = key < best ? key : best;
            }
        }
    }

    // Wave-level reduce (wave = 64 lanes on CDNA)
    #pragma unroll
    for (int off = 32; off > 0; off >>= 1) {
        const unsigned long long o = __shfl_down(best, off, 64);
        best = o < best ? o : best;
    }
    const int lane = tid & 63;
    const int wv   = tid >> 6;
    if (lane == 0) wred[wv] = best;
    __syncthreads();
    if (tid == 0) {
        unsigned long long m = wred[0];
        m = wred[1] < m ? wred[1] : m;
        m = wred[2] < m ? wred[2] : m;
        m = wred[3] < m ? wred[3] : m;
        win_start = (int)(m & 0xffffffffu);
    }
    __syncthreads();

    // Emit winning window (bit-exact copy of input)
    if (tid < L_SZ)
        out[(size_t)b * L_SZ + tid] = xs[win_start + tid];
}

extern "C" void kernel_launch(void* const* d_in, const int* in_sizes, int n_in,
                              void* d_out, int out_size, void* d_ws, size_t ws_size,
                              hipStream_t stream) {
    // Input order: feats_in (unused), X_in, feats_out (unused), X_out
    const float* X_in  = (const float*)d_in[1];
    const float* X_out = (const float*)d_in[3];
    float* out = (float*)d_out;

    window_match_kernel<<<B_SZ, 256, 0, stream>>>(X_in, X_out, out);
}

// Round 2
// 65.046 us; speedup vs baseline: 1.1297x; 1.1297x over previous
//
#include <hip/hip_runtime.h>
#include <hip/hip_bf16.h>

// Problem constants: B=64, T=8192, L=64, NWIN=8128 = 4 * 2032
constexpr int B_SZ  = 64;
constexpr int T_SZ  = 8192;
constexpr int L_SZ  = 64;
constexpr int NWIN  = T_SZ - L_SZ;   // 8128
constexpr int NQ    = 4;             // quarters per batch
constexpr int QW    = NWIN / NQ;     // 2032 windows per quarter
constexpr int STAGE = QW + L_SZ;     // 2096 floats staged per block

// Kernel 1: 256 blocks (B*NQ), one per (batch, quarter). Each block stages its
// x-slice in LDS, evaluates 2032 windows, block-reduces to one packed u64 key
// ((float_bits(dist)<<32)|global_start — dist>=0 so u64 order == (dist, idx)
// lexicographic order, ties -> smallest index, matching np.argmin), and writes
// it to ws_keys[b*NQ+q].
__global__ __launch_bounds__(256)
void window_match_partial(const float* __restrict__ X_in,
                          const float* __restrict__ X_out,
                          unsigned long long* __restrict__ ws_keys)
{
    __shared__ float xs[STAGE + 16];           // ~8.4 KB
    __shared__ float ys[L_SZ];
    __shared__ unsigned long long wred[4];

    const int bq  = blockIdx.x;
    const int b   = bq >> 2;
    const int q   = bq & 3;
    const int tid = threadIdx.x;
    const int base = q * QW;                   // 2032*q, divisible by 4

    // Stage x[b, base .. base+2095] via float4 (524 vec4 loads over 256 threads)
    const float4* xg  = reinterpret_cast<const float4*>(X_in + (size_t)b * T_SZ + base);
    float4*       xs4 = reinterpret_cast<float4*>(xs);
    for (int i = tid; i < STAGE / 4; i += 256)
        xs4[i] = xg[i];

    if (tid < L_SZ) ys[tid] = X_out[(size_t)b * L_SZ + tid];
    __syncthreads();

    float y[L_SZ];
    #pragma unroll
    for (int j = 0; j < L_SZ; ++j) y[j] = ys[j];

    unsigned long long best = ~0ull;

    // 2 rounds x 256 threads x 4 windows = 2048 slots >= 2032 windows.
    // Groups of 4 never straddle the 2032 boundary (2032 % 4 == 0).
    #pragma unroll
    for (int k = 0; k < 2; ++k) {
        const int s0 = 4 * tid + 1024 * k;     // local window start, float4-aligned
        if (s0 < QW) {
            float xv[68];
            const float4* p = reinterpret_cast<const float4*>(xs + s0);
            #pragma unroll
            for (int i = 0; i < 17; ++i) {
                float4 v = p[i];
                xv[4 * i + 0] = v.x;
                xv[4 * i + 1] = v.y;
                xv[4 * i + 2] = v.z;
                xv[4 * i + 3] = v.w;
            }
            #pragma unroll
            for (int w = 0; w < 4; ++w) {
                float d = 0.0f;
                #pragma unroll
                for (int j = 0; j < L_SZ; ++j) {
                    const float t = xv[w + j] - y[j];
                    d = fmaf(t, t, d);
                }
                const unsigned long long key =
                    ((unsigned long long)__float_as_uint(d) << 32) |
                    (unsigned int)(base + s0 + w);
                best = key < best ? key : best;
            }
        }
    }

    // Wave (64-lane) shuffle reduce, then cross-wave via LDS
    #pragma unroll
    for (int off = 32; off > 0; off >>= 1) {
        const unsigned long long o = __shfl_down(best, off, 64);
        best = o < best ? o : best;
    }
    if ((tid & 63) == 0) wred[tid >> 6] = best;
    __syncthreads();
    if (tid == 0) {
        unsigned long long m = wred[0];
        m = wred[1] < m ? wred[1] : m;
        m = wred[2] < m ? wred[2] : m;
        m = wred[3] < m ? wred[3] : m;
        ws_keys[bq] = m;
    }
}

// Kernel 2: 64 blocks x 64 threads. Each block min-reduces its batch's 4 quarter
// keys (all threads redundantly — 4 broadcast loads, no sync needed) and copies
// the winning 64-float window from global X_in (bit-exact copy of input).
__global__ __launch_bounds__(64)
void window_match_gather(const float* __restrict__ X_in,
                         const unsigned long long* __restrict__ ws_keys,
                         float* __restrict__ out)
{
    const int b   = blockIdx.x;
    const int tid = threadIdx.x;

    unsigned long long m = ws_keys[b * NQ + 0];
    #pragma unroll
    for (int qq = 1; qq < NQ; ++qq) {
        const unsigned long long o = ws_keys[b * NQ + qq];
        m = o < m ? o : m;
    }
    const int s = (int)(m & 0xffffffffu);
    out[(size_t)b * L_SZ + tid] = X_in[(size_t)b * T_SZ + s + tid];
}

extern "C" void kernel_launch(void* const* d_in, const int* in_sizes, int n_in,
                              void* d_out, int out_size, void* d_ws, size_t ws_size,
                              hipStream_t stream) {
    // Input order: feats_in (unused), X_in, feats_out (unused), X_out
    const float* X_in  = (const float*)d_in[1];
    const float* X_out = (const float*)d_in[3];
    float* out = (float*)d_out;
    unsigned long long* ws_keys = (unsigned long long*)d_ws;   // 256 * 8 B

    window_match_partial<<<B_SZ * NQ, 256, 0, stream>>>(X_in, X_out, ws_keys);
    window_match_gather<<<B_SZ, 64, 0, stream>>>(X_in, ws_keys, out);
}